// Round 8
// baseline (1102.213 us; speedup 1.0000x reference)
//
#include <hip/hip_runtime.h>

#define N_PTS 4096
#define NB    8
#define KNN   20
#define FIN   67
#define COUT  64

typedef unsigned short u16;
typedef unsigned int   u32;
typedef unsigned long long u64;

__device__ __forceinline__ u32 umin32(u32 a, u32 b) { return a < b ? a : b; }

// Order-preserving f32 -> u32 map (no NaNs in finite-distance data).
__device__ __forceinline__ u32 fmap(float f) {
    u32 b = __float_as_uint(f);
    return b ^ ((u32)((int)b >> 31) | 0x80000000u);
}

template <int CTRL>
__device__ __forceinline__ u32 dpp_mov(u32 v) {
    return (u32)__builtin_amdgcn_update_dpp((int)v, (int)v, CTRL, 0xF, 0xF, false);
}

// Min across all 64 lanes, returned uniform. 4 DPP row_ror steps (VALU) +
// 4 readlane + scalar mins — NO DS ops (replaces the 120-cy-latency
// ds_swizzle chains of __shfl_xor).
__device__ __forceinline__ u32 wave_min_u32(u32 v) {
    v = umin32(v, dpp_mov<0x121>(v));   // row_ror:1
    v = umin32(v, dpp_mov<0x122>(v));   // row_ror:2
    v = umin32(v, dpp_mov<0x124>(v));   // row_ror:4
    v = umin32(v, dpp_mov<0x128>(v));   // row_ror:8  -> row16 min in every lane
    u32 a = (u32)__builtin_amdgcn_readlane((int)v, 0);
    u32 b = (u32)__builtin_amdgcn_readlane((int)v, 16);
    u32 c = (u32)__builtin_amdgcn_readlane((int)v, 32);
    u32 d = (u32)__builtin_amdgcn_readlane((int)v, 48);
    return umin32(umin32(a, b), umin32(c, d));
}

// sq = (x*x + y*y) + z*z, all f32, no FMA (matches np op order).
__device__ __forceinline__ float sq_exact(float x, float y, float z) {
#pragma clang fp contract(off)
    float s = (x * x + y * y) + z * z;
    return s;
}

// dist = (sq_i - 2*dot) + sq_j, dot = (x_i*x_j + y_i*y_j) + z_i*z_j, no FMA.
__device__ __forceinline__ float dist_exact(float xi, float yi, float zi, float sqi,
                                            float xj, float yj, float zj) {
#pragma clang fp contract(off)
    float d0 = xi * xj, d1 = yi * yj, d2 = zi * zj;
    float dot = (d0 + d1) + d2;
    float sqj = (xj * xj + yj * yj) + zj * zj;
    float d = (sqi - 2.0f * dot) + sqj;
    return d;
}

__device__ __forceinline__ void insert3(float d, int c,
                                        float& v0, float& v1, float& v2,
                                        int& c0, int& c1, int& c2) {
    if (d < v2) {
        if (d < v1) {
            if (d < v0) { v2 = v1; c2 = c1; v1 = v0; c1 = c0; v0 = d; c0 = c; }
            else        { v2 = v1; c2 = c1; v1 = d;  c1 = c; }
        } else          { v2 = d;  c2 = c; }
    }
}

// ---------------- Kernel 1: kNN selection only ----------------
// One wave per point. Distance pass identical to the proven round-6 kernel;
// selection rounds use DPP+scalar reductions (no DS-chain latency).
__global__ __launch_bounds__(64) void knn_kernel(
    const float* __restrict__ xloc, u16* __restrict__ knn_out) {
    const int lane = threadIdx.x;
    const int row  = blockIdx.x;          // b*4096 + i
    const int b    = row >> 12;
    const int i    = row & (N_PTS - 1);
    const float* xb = xloc + (size_t)b * 3 * N_PTS;

    const float xi  = xb[i];
    const float yi  = xb[N_PTS + i];
    const float zi  = xb[2 * N_PTS + i];
    const float sqi = sq_exact(xi, yi, zi);

    // Per-lane sorted top-3 over its 64 candidates.
    // Candidate c (0..63) -> global j = (c>>2)*256 + lane*4 + (c&3)
    float v0 = 1e30f, v1 = 1e30f, v2 = 1e30f;
    int   c0 = -1,    c1 = -1,    c2 = -1;

    for (int s = 0; s < 16; ++s) {
        int jb = s * 256 + lane * 4;
        float4 fx = *(const float4*)(xb + jb);
        float4 fy = *(const float4*)(xb + N_PTS + jb);
        float4 fz = *(const float4*)(xb + 2 * N_PTS + jb);
#pragma unroll
        for (int q = 0; q < 4; ++q) {
            float xj = (q == 0) ? fx.x : (q == 1) ? fx.y : (q == 2) ? fx.z : fx.w;
            float yj = (q == 0) ? fy.x : (q == 1) ? fy.y : (q == 2) ? fy.z : fy.w;
            float zj = (q == 0) ? fz.x : (q == 1) ? fz.y : (q == 2) ? fz.z : fz.w;
            int j = jb + q;
            float d = (j == i) ? 1e30f : dist_exact(xi, yi, zi, sqi, xj, yj, zj);
            insert3(d, s * 4 + q, v0, v1, v2, c0, c1, c2);
        }
    }

    u64 taken = 0;
    int myknn = 0;

    for (int t = 0; t < KNN; ++t) {
        // (dist, idx) lexicographic argmin across the wave, DPP+scalar:
        u32 key  = fmap(v0);
        int j0   = (c0 >= 0) ? (((c0 >> 2) << 8) + lane * 4 + (c0 & 3)) : 0x3FFFFFFF;
        u32 smin = wave_min_u32(key);
        u32 myj  = (key == smin) ? (u32)j0 : 0x7FFFFFFFu;
        u32 jmin = wave_min_u32(myj);

        if (lane == t) myknn = (int)jmin;    // winner index (uniform value)

        bool owner = (key == smin) && ((u32)j0 == jmin);
        if (owner) {
            int cw = (((j0 >> 8) << 2) | (j0 & 3)) & 63;
            taken |= (1ull << cw);
            v0 = v1; c0 = c1; v1 = v2; c1 = c2; v2 = 1e30f; c2 = -1;
            if (v0 >= 1e30f) {
                // Rare: rebuild top-3 from remaining candidates (identical rounding).
                v0 = v1 = v2 = 1e30f; c0 = c1 = c2 = -1;
                for (int s = 0; s < 16; ++s) {
                    int jb = s * 256 + lane * 4;
                    float4 fx = *(const float4*)(xb + jb);
                    float4 fy = *(const float4*)(xb + N_PTS + jb);
                    float4 fz = *(const float4*)(xb + 2 * N_PTS + jb);
#pragma unroll
                    for (int q = 0; q < 4; ++q) {
                        int cc = s * 4 + q;
                        if ((taken >> cc) & 1ull) continue;
                        int j = jb + q;
                        if (j == i) continue;
                        float xj = (q == 0) ? fx.x : (q == 1) ? fx.y : (q == 2) ? fx.z : fx.w;
                        float yj = (q == 0) ? fy.x : (q == 1) ? fy.y : (q == 2) ? fy.z : fy.w;
                        float zj = (q == 0) ? fz.x : (q == 1) ? fz.y : (q == 2) ? fz.z : fz.w;
                        float d = dist_exact(xi, yi, zi, sqi, xj, yj, zj);
                        insert3(d, cc, v0, v1, v2, c0, c1, c2);
                    }
                }
            }
        }
    }

    if (lane < KNN) knn_out[(size_t)row * KNN + lane] = (u16)myknn;
}

// ---------------- Kernel 2: gather + GEMV epilogue, fully coalesced ----------------
// Block = 64 consecutive points of one batch; lane = point. agg/h live in
// statically-indexed registers; W is uniform (scalar loads). All global
// writes are lane-consecutive (full 256B lines) -> no write amplification.
__global__ __launch_bounds__(64) void conv_kernel(
    const float* __restrict__ xloc,
    const float* __restrict__ xfeat,
    const float* __restrict__ Wrel,
    const float* __restrict__ brel,
    const float* __restrict__ Wroot,
    const u16* __restrict__ knn_in,
    float* __restrict__ out) {
    const int lane = threadIdx.x;
    const int blk  = blockIdx.x;              // b*64 + tile
    const int b    = blk >> 6;
    const int i    = ((blk & 63) << 6) | lane;  // point index within batch
    const float* xb = xloc + (size_t)b * 3 * N_PTS;
    const float* fb = xfeat + (size_t)b * 64 * N_PTS;

    // Output 0 passthrough (bit-exact, coalesced).
#pragma unroll
    for (int c = 0; c < 3; ++c)
        out[((size_t)b * 3 + c) * N_PTS + i] = xb[(size_t)c * N_PTS + i];

    float agg[FIN];
    float h[FIN];
#pragma unroll
    for (int f = 0; f < FIN; ++f) agg[f] = 0.f;
#pragma unroll
    for (int c = 0; c < 3; ++c) h[c] = xb[(size_t)c * N_PTS + i];
#pragma unroll
    for (int f = 0; f < 64; ++f) h[3 + f] = fb[(size_t)f * N_PTS + i];

    const u16* kl = knn_in + (size_t)(b * N_PTS + i) * KNN;
    for (int t = 0; t < KNN; ++t) {           // ascending (dist, idx) order
        int j = kl[t];
#pragma unroll
        for (int c = 0; c < 3; ++c) agg[c] += xb[(size_t)c * N_PTS + j];
#pragma unroll
        for (int f = 0; f < 64; ++f) agg[3 + f] += fb[(size_t)f * N_PTS + j];
    }

    const size_t ob = (size_t)NB * 3 * N_PTS + (size_t)b * COUT * N_PTS;
    for (int c = 0; c < COUT; ++c) {
        float ar = 0.f, ao = 0.f;
#pragma unroll
        for (int f = 0; f < FIN; ++f) {
            ar += agg[f] * Wrel[f * COUT + c];
            ao += h[f]   * Wroot[f * COUT + c];
        }
        float acc = (ar + brel[c]) + ao;      // einsum + b_rel + einsum order
        out[ob + (size_t)c * N_PTS + i] = fmaxf(acc, 0.f);
    }
}

// ---------------- Fallback: proven round-6 monolithic kernel ----------------
__global__ __launch_bounds__(64) void pcd_all(
    const float* __restrict__ xloc,
    const float* __restrict__ xfeat,
    const float* __restrict__ Wrel,
    const float* __restrict__ brel,
    const float* __restrict__ Wroot,
    float* __restrict__ out) {
    const int lane = threadIdx.x;
    const int row  = blockIdx.x;
    const int b    = row >> 12;
    const int i    = row & (N_PTS - 1);
    const float* xb = xloc + (size_t)b * 3 * N_PTS;

    if (lane < 3) {
        out[((size_t)b * 3 + lane) * N_PTS + i] = xb[(size_t)lane * N_PTS + i];
    }

    const float xi  = xb[i];
    const float yi  = xb[N_PTS + i];
    const float zi  = xb[2 * N_PTS + i];
    const float sqi = sq_exact(xi, yi, zi);

    float v0 = 1e30f, v1 = 1e30f, v2 = 1e30f;
    int   c0 = -1,    c1 = -1,    c2 = -1;

    for (int s = 0; s < 16; ++s) {
        int jb = s * 256 + lane * 4;
        float4 fx = *(const float4*)(xb + jb);
        float4 fy = *(const float4*)(xb + N_PTS + jb);
        float4 fz = *(const float4*)(xb + 2 * N_PTS + jb);
#pragma unroll
        for (int q = 0; q < 4; ++q) {
            float xj = (q == 0) ? fx.x : (q == 1) ? fx.y : (q == 2) ? fx.z : fx.w;
            float yj = (q == 0) ? fy.x : (q == 1) ? fy.y : (q == 2) ? fy.z : fy.w;
            float zj = (q == 0) ? fz.x : (q == 1) ? fz.y : (q == 2) ? fz.z : fz.w;
            int j = jb + q;
            float d = (j == i) ? 1e30f : dist_exact(xi, yi, zi, sqi, xj, yj, zj);
            insert3(d, s * 4 + q, v0, v1, v2, c0, c1, c2);
        }
    }

    u64 taken = 0;
    __shared__ int knn[KNN];

    for (int t = 0; t < KNN; ++t) {
        float bv = v0;
        int   bj = (c0 >= 0) ? (((c0 >> 2) << 8) + lane * 4 + (c0 & 3)) : (N_PTS - 1);
#pragma unroll
        for (int m = 1; m < 64; m <<= 1) {
            float ov = __shfl_xor(bv, m);
            int   oj = __shfl_xor(bj, m);
            if (ov < bv || (ov == bv && oj < bj)) { bv = ov; bj = oj; }
        }
        if (lane == 0) knn[t] = bj & (N_PTS - 1);
        int owner = (bj >> 2) & 63;
        if (lane == owner) {
            int cw = (((bj >> 8) << 2) | (bj & 3)) & 63;
            taken |= (1ull << cw);
            v0 = v1; c0 = c1; v1 = v2; c1 = c2; v2 = 1e30f; c2 = -1;
            if (v0 >= 1e30f) {
                v0 = v1 = v2 = 1e30f; c0 = c1 = c2 = -1;
                for (int s = 0; s < 16; ++s) {
                    int jb = s * 256 + lane * 4;
                    float4 fx = *(const float4*)(xb + jb);
                    float4 fy = *(const float4*)(xb + N_PTS + jb);
                    float4 fz = *(const float4*)(xb + 2 * N_PTS + jb);
#pragma unroll
                    for (int q = 0; q < 4; ++q) {
                        int cc = s * 4 + q;
                        if ((taken >> cc) & 1ull) continue;
                        int j = jb + q;
                        if (j == i) continue;
                        float xj = (q == 0) ? fx.x : (q == 1) ? fx.y : (q == 2) ? fx.z : fx.w;
                        float yj = (q == 0) ? fy.x : (q == 1) ? fy.y : (q == 2) ? fy.z : fy.w;
                        float zj = (q == 0) ? fz.x : (q == 1) ? fz.y : (q == 2) ? fz.z : fz.w;
                        float d = dist_exact(xi, yi, zi, sqi, xj, yj, zj);
                        insert3(d, cc, v0, v1, v2, c0, c1, c2);
                    }
                }
            }
        }
    }

    __syncthreads();

    __shared__ float aggf[FIN + 1];
    __shared__ float hif[FIN + 1];

    const float* xfb = xfeat + ((size_t)b * 64 + lane) * N_PTS;
    const float* xlb = xb + (size_t)(lane < 3 ? lane : 0) * N_PTS;
    float af = 0.f, al = 0.f;
    for (int t = 0; t < KNN; ++t) {
        int j = knn[t];
        af += xfb[j];
        if (lane < 3) al += xlb[j];
    }
    aggf[3 + lane] = af;
    hif[3 + lane]  = xfb[i];
    if (lane < 3) { aggf[lane] = al; hif[lane] = xlb[i]; }
    __syncthreads();

    float acc_rel = 0.f, acc_root = 0.f;
    for (int f = 0; f < FIN; ++f) {
        acc_rel  += aggf[f] * Wrel[f * COUT + lane];
        acc_root += hif[f]  * Wroot[f * COUT + lane];
    }
    float acc = (acc_rel + brel[lane]) + acc_root;
    acc = fmaxf(acc, 0.0f);
    out[(size_t)NB * 3 * N_PTS + ((((size_t)b << 6) | lane) << 12) + i] = acc;
}

extern "C" void kernel_launch(void* const* d_in, const int* in_sizes, int n_in,
                              void* d_out, int out_size, void* d_ws, size_t ws_size,
                              hipStream_t stream) {
    const float* xloc  = nullptr;
    const float* xfeat = nullptr;
    const float* Wrel  = nullptr;
    const float* brel  = nullptr;
    const float* Wroot = nullptr;
    for (int idx = 0; idx < n_in; ++idx) {
        const long long s = in_sizes[idx];
        const float* p = (const float*)d_in[idx];
        if (s == 98304LL || s == 393216LL)          { xloc = p; }
        else if (s == 2097152LL || s == 8388608LL)  { xfeat = p; }
        else if (s == 4288LL || s == 17152LL)       { if (!Wrel) Wrel = p; else Wroot = p; }
        else if (s == 64LL || s == 256LL)           { brel = p; }
    }
    if (!xloc || !xfeat || !Wrel || !brel || !Wroot) {
        xloc  = (const float*)d_in[0];
        xfeat = (const float*)d_in[1];
        Wrel  = (const float*)d_in[2];
        brel  = (const float*)d_in[3];
        Wroot = (const float*)d_in[4];
    }

    const size_t KNN_BYTES = (size_t)NB * N_PTS * KNN * sizeof(u16);  // 1.31 MB
    if (d_ws != nullptr && ws_size >= KNN_BYTES) {
        u16* knn_ws = (u16*)d_ws;
        knn_kernel<<<dim3(NB * N_PTS), dim3(64), 0, stream>>>(xloc, knn_ws);
        conv_kernel<<<dim3(NB * 64), dim3(64), 0, stream>>>(
            xloc, xfeat, Wrel, brel, Wroot, knn_ws, (float*)d_out);
    } else {
        pcd_all<<<dim3(NB * N_PTS), dim3(64), 0, stream>>>(
            xloc, xfeat, Wrel, brel, Wroot, (float*)d_out);
    }
}

// Round 9
// 1073.156 us; speedup vs baseline: 1.0271x; 1.0271x over previous
//
#include <hip/hip_runtime.h>

#define N_PTS 4096
#define NB    8
#define KNN   20
#define FIN   67
#define COUT  64

typedef unsigned short u16;
typedef unsigned int   u32;
typedef unsigned long long u64;

__device__ __forceinline__ u32 umin32(u32 a, u32 b) { return a < b ? a : b; }

// Order-preserving f32 -> u32 map (no NaNs in finite-distance data).
__device__ __forceinline__ u32 fmap(float f) {
    u32 b = __float_as_uint(f);
    return b ^ ((u32)((int)b >> 31) | 0x80000000u);
}

template <int CTRL>
__device__ __forceinline__ u32 dpp_mov(u32 v) {
    return (u32)__builtin_amdgcn_update_dpp((int)v, (int)v, CTRL, 0xF, 0xF, false);
}

// Min across all 64 lanes, returned uniform (proven in round 8).
__device__ __forceinline__ u32 wave_min_u32(u32 v) {
    v = umin32(v, dpp_mov<0x121>(v));   // row_ror:1
    v = umin32(v, dpp_mov<0x122>(v));   // row_ror:2
    v = umin32(v, dpp_mov<0x124>(v));   // row_ror:4
    v = umin32(v, dpp_mov<0x128>(v));   // row_ror:8  -> row16 min in every lane
    u32 a = (u32)__builtin_amdgcn_readlane((int)v, 0);
    u32 b = (u32)__builtin_amdgcn_readlane((int)v, 16);
    u32 c = (u32)__builtin_amdgcn_readlane((int)v, 32);
    u32 d = (u32)__builtin_amdgcn_readlane((int)v, 48);
    return umin32(umin32(a, b), umin32(c, d));
}

// sq = (x*x + y*y) + z*z, all f32, no FMA (matches np op order).
__device__ __forceinline__ float sq_exact(float x, float y, float z) {
#pragma clang fp contract(off)
    float s = (x * x + y * y) + z * z;
    return s;
}

// Full np-exact distance (recomputes sqj) — used in rare refill path.
__device__ __forceinline__ float dist_exact(float xi, float yi, float zi, float sqi,
                                            float xj, float yj, float zj) {
#pragma clang fp contract(off)
    float d0 = xi * xj, d1 = yi * yj, d2 = zi * zj;
    float dot = (d0 + d1) + d2;
    float sqj = (xj * xj + yj * yj) + zj * zj;
    float d = (sqi - 2.0f * dot) + sqj;
    return d;
}

// Distance with precomputed sqj (bit-identical value, same op order).
__device__ __forceinline__ float dist_from_sq(float xi, float yi, float zi, float sqi,
                                              float xj, float yj, float zj, float sqj) {
#pragma clang fp contract(off)
    float d0 = xi * xj, d1 = yi * yj, d2 = zi * zj;
    float dot = (d0 + d1) + d2;
    float d = (sqi - 2.0f * dot) + sqj;
    return d;
}

__device__ __forceinline__ void insert3(float d, int c,
                                        float& v0, float& v1, float& v2,
                                        int& c0, int& c1, int& c2) {
    if (d < v2) {
        if (d < v1) {
            if (d < v0) { v2 = v1; c2 = c1; v1 = v0; c1 = c0; v0 = d; c0 = c; }
            else        { v2 = v1; c2 = c1; v1 = d;  c1 = c; }
        } else          { v2 = d;  c2 = c; }
    }
}

// ---------------- Kernel 1: kNN for FOUR points per wave ----------------
// One candidate stream (48 KB of xb) serves 4 query points -> 4x less L1/L2
// load traffic per point (the round-8 bottleneck). Extraction chains for the
// 4 points are independent and interleave.
__global__ __launch_bounds__(64) void knn4_kernel(
    const float* __restrict__ xloc, u16* __restrict__ knn_out) {
    const int lane  = threadIdx.x;
    const int base  = blockIdx.x << 2;        // global point id of p=0 (batch-aligned)
    const int b     = base >> 12;
    const int ibase = base & (N_PTS - 1);
    const float* xb = xloc + (size_t)b * 3 * N_PTS;

    float xi[4], yi[4], zi[4], sqi[4];
#pragma unroll
    for (int p = 0; p < 4; ++p) {
        int i = ibase + p;
        xi[p] = xb[i]; yi[p] = xb[N_PTS + i]; zi[p] = xb[2 * N_PTS + i];
        sqi[p] = sq_exact(xi[p], yi[p], zi[p]);
    }

    float v0[4], v1[4], v2[4];
    int   c0[4], c1[4], c2[4];
#pragma unroll
    for (int p = 0; p < 4; ++p) { v0[p] = v1[p] = v2[p] = 1e30f; c0[p] = c1[p] = c2[p] = -1; }

    for (int s = 0; s < 16; ++s) {
        int jb = s * 256 + lane * 4;
        float4 fx = *(const float4*)(xb + jb);
        float4 fy = *(const float4*)(xb + N_PTS + jb);
        float4 fz = *(const float4*)(xb + 2 * N_PTS + jb);
#pragma unroll
        for (int q = 0; q < 4; ++q) {
            float xj = (q == 0) ? fx.x : (q == 1) ? fx.y : (q == 2) ? fx.z : fx.w;
            float yj = (q == 0) ? fy.x : (q == 1) ? fy.y : (q == 2) ? fy.z : fy.w;
            float zj = (q == 0) ? fz.x : (q == 1) ? fz.y : (q == 2) ? fz.z : fz.w;
            float sqj = sq_exact(xj, yj, zj);     // once per candidate, shared by 4 queries
            int j = jb + q;
#pragma unroll
            for (int p = 0; p < 4; ++p) {
                float d = (j == ibase + p) ? 1e30f
                        : dist_from_sq(xi[p], yi[p], zi[p], sqi[p], xj, yj, zj, sqj);
                insert3(d, s * 4 + q, v0[p], v1[p], v2[p], c0[p], c1[p], c2[p]);
            }
        }
    }

    u64 taken[4] = {0, 0, 0, 0};
    int myknn[4] = {0, 0, 0, 0};

    for (int t = 0; t < KNN; ++t) {
#pragma unroll
        for (int p = 0; p < 4; ++p) {
            u32 key  = fmap(v0[p]);
            int j0   = (c0[p] >= 0) ? (((c0[p] >> 2) << 8) + lane * 4 + (c0[p] & 3))
                                    : 0x3FFFFFFF;
            u32 smin = wave_min_u32(key);
            u32 myj  = (key == smin) ? (u32)j0 : 0x7FFFFFFFu;
            u32 jmin = wave_min_u32(myj);

            if (lane == t) myknn[p] = (int)jmin;

            bool owner = (key == smin) && ((u32)j0 == jmin);
            if (owner) {
                int cw = (((j0 >> 8) << 2) | (j0 & 3)) & 63;
                taken[p] |= (1ull << cw);
                v0[p] = v1[p]; c0[p] = c1[p];
                v1[p] = v2[p]; c1[p] = c2[p];
                v2[p] = 1e30f; c2[p] = -1;
                if (v0[p] >= 1e30f) {
                    // Rare: rebuild top-3 from remaining candidates (identical rounding).
                    v0[p] = v1[p] = v2[p] = 1e30f; c0[p] = c1[p] = c2[p] = -1;
                    for (int s = 0; s < 16; ++s) {
                        int jb = s * 256 + lane * 4;
                        float4 fx = *(const float4*)(xb + jb);
                        float4 fy = *(const float4*)(xb + N_PTS + jb);
                        float4 fz = *(const float4*)(xb + 2 * N_PTS + jb);
#pragma unroll
                        for (int q = 0; q < 4; ++q) {
                            int cc = s * 4 + q;
                            if ((taken[p] >> cc) & 1ull) continue;
                            int j = jb + q;
                            if (j == ibase + p) continue;
                            float xj = (q == 0) ? fx.x : (q == 1) ? fx.y : (q == 2) ? fx.z : fx.w;
                            float yj = (q == 0) ? fy.x : (q == 1) ? fy.y : (q == 2) ? fy.z : fy.w;
                            float zj = (q == 0) ? fz.x : (q == 1) ? fz.y : (q == 2) ? fz.z : fz.w;
                            float d = dist_exact(xi[p], yi[p], zi[p], sqi[p], xj, yj, zj);
                            insert3(d, cc, v0[p], v1[p], v2[p], c0[p], c1[p], c2[p]);
                        }
                    }
                }
            }
        }
    }

#pragma unroll
    for (int p = 0; p < 4; ++p)
        if (lane < KNN) knn_out[(size_t)(base + p) * KNN + lane] = (u16)myknn[p];
}

// ---------------- Kernel 2: gather + GEMV (proven round-7 tail) ----------------
__global__ __launch_bounds__(64) void conv_kernel(
    const float* __restrict__ xloc,
    const float* __restrict__ xfeat,
    const float* __restrict__ Wrel,
    const float* __restrict__ brel,
    const float* __restrict__ Wroot,
    const u16* __restrict__ knn_in,
    float* __restrict__ out) {
    const int lane = threadIdx.x;
    const int row  = blockIdx.x;
    const int b    = row >> 12;
    const int i    = row & (N_PTS - 1);
    const float* xb = xloc + (size_t)b * 3 * N_PTS;

    if (lane < 3) {
        out[((size_t)b * 3 + lane) * N_PTS + i] = xb[(size_t)lane * N_PTS + i];
    }

    __shared__ int knn[KNN];
    if (lane < KNN) knn[lane] = knn_in[(size_t)row * KNN + lane];
    __syncthreads();

    __shared__ float aggf[FIN + 1];
    __shared__ float hif[FIN + 1];

    const float* xfb = xfeat + ((size_t)b * 64 + lane) * N_PTS;
    const float* xlb = xb + (size_t)(lane < 3 ? lane : 0) * N_PTS;
    float af = 0.f, al = 0.f;
    for (int t = 0; t < KNN; ++t) {            // ascending (dist, idx) order
        int j = knn[t];
        af += xfb[j];
        if (lane < 3) al += xlb[j];
    }
    aggf[3 + lane] = af;
    hif[3 + lane]  = xfb[i];
    if (lane < 3) { aggf[lane] = al; hif[lane] = xlb[i]; }
    __syncthreads();

    float acc_rel = 0.f, acc_root = 0.f;
    for (int f = 0; f < FIN; ++f) {
        acc_rel  += aggf[f] * Wrel[f * COUT + lane];
        acc_root += hif[f]  * Wroot[f * COUT + lane];
    }
    float acc = (acc_rel + brel[lane]) + acc_root;  // einsum + b_rel + einsum order
    acc = fmaxf(acc, 0.0f);
    out[(size_t)NB * 3 * N_PTS + ((((size_t)b << 6) | lane) << 12) + i] = acc;
}

// ---------------- Fallback: proven round-6/7 monolithic kernel ----------------
__global__ __launch_bounds__(64) void pcd_all(
    const float* __restrict__ xloc,
    const float* __restrict__ xfeat,
    const float* __restrict__ Wrel,
    const float* __restrict__ brel,
    const float* __restrict__ Wroot,
    float* __restrict__ out) {
    const int lane = threadIdx.x;
    const int row  = blockIdx.x;
    const int b    = row >> 12;
    const int i    = row & (N_PTS - 1);
    const float* xb = xloc + (size_t)b * 3 * N_PTS;

    if (lane < 3) {
        out[((size_t)b * 3 + lane) * N_PTS + i] = xb[(size_t)lane * N_PTS + i];
    }

    const float xi  = xb[i];
    const float yi  = xb[N_PTS + i];
    const float zi  = xb[2 * N_PTS + i];
    const float sqi = sq_exact(xi, yi, zi);

    float v0 = 1e30f, v1 = 1e30f, v2 = 1e30f;
    int   c0 = -1,    c1 = -1,    c2 = -1;

    for (int s = 0; s < 16; ++s) {
        int jb = s * 256 + lane * 4;
        float4 fx = *(const float4*)(xb + jb);
        float4 fy = *(const float4*)(xb + N_PTS + jb);
        float4 fz = *(const float4*)(xb + 2 * N_PTS + jb);
#pragma unroll
        for (int q = 0; q < 4; ++q) {
            float xj = (q == 0) ? fx.x : (q == 1) ? fx.y : (q == 2) ? fx.z : fx.w;
            float yj = (q == 0) ? fy.x : (q == 1) ? fy.y : (q == 2) ? fy.z : fy.w;
            float zj = (q == 0) ? fz.x : (q == 1) ? fz.y : (q == 2) ? fz.z : fz.w;
            int j = jb + q;
            float d = (j == i) ? 1e30f : dist_exact(xi, yi, zi, sqi, xj, yj, zj);
            insert3(d, s * 4 + q, v0, v1, v2, c0, c1, c2);
        }
    }

    u64 taken = 0;
    __shared__ int knn[KNN];

    for (int t = 0; t < KNN; ++t) {
        float bv = v0;
        int   bj = (c0 >= 0) ? (((c0 >> 2) << 8) + lane * 4 + (c0 & 3)) : (N_PTS - 1);
#pragma unroll
        for (int m = 1; m < 64; m <<= 1) {
            float ov = __shfl_xor(bv, m);
            int   oj = __shfl_xor(bj, m);
            if (ov < bv || (ov == bv && oj < bj)) { bv = ov; bj = oj; }
        }
        if (lane == 0) knn[t] = bj & (N_PTS - 1);
        int owner = (bj >> 2) & 63;
        if (lane == owner) {
            int cw = (((bj >> 8) << 2) | (bj & 3)) & 63;
            taken |= (1ull << cw);
            v0 = v1; c0 = c1; v1 = v2; c1 = c2; v2 = 1e30f; c2 = -1;
            if (v0 >= 1e30f) {
                v0 = v1 = v2 = 1e30f; c0 = c1 = c2 = -1;
                for (int s = 0; s < 16; ++s) {
                    int jb = s * 256 + lane * 4;
                    float4 fx = *(const float4*)(xb + jb);
                    float4 fy = *(const float4*)(xb + N_PTS + jb);
                    float4 fz = *(const float4*)(xb + 2 * N_PTS + jb);
#pragma unroll
                    for (int q = 0; q < 4; ++q) {
                        int cc = s * 4 + q;
                        if ((taken >> cc) & 1ull) continue;
                        int j = jb + q;
                        if (j == i) continue;
                        float xj = (q == 0) ? fx.x : (q == 1) ? fx.y : (q == 2) ? fx.z : fx.w;
                        float yj = (q == 0) ? fy.x : (q == 1) ? fy.y : (q == 2) ? fy.z : fy.w;
                        float zj = (q == 0) ? fz.x : (q == 1) ? fz.y : (q == 2) ? fz.z : fz.w;
                        float d = dist_exact(xi, yi, zi, sqi, xj, yj, zj);
                        insert3(d, cc, v0, v1, v2, c0, c1, c2);
                    }
                }
            }
        }
    }

    __syncthreads();

    __shared__ float aggf[FIN + 1];
    __shared__ float hif[FIN + 1];

    const float* xfb = xfeat + ((size_t)b * 64 + lane) * N_PTS;
    const float* xlb = xb + (size_t)(lane < 3 ? lane : 0) * N_PTS;
    float af = 0.f, al = 0.f;
    for (int t = 0; t < KNN; ++t) {
        int j = knn[t];
        af += xfb[j];
        if (lane < 3) al += xlb[j];
    }
    aggf[3 + lane] = af;
    hif[3 + lane]  = xfb[i];
    if (lane < 3) { aggf[lane] = al; hif[lane] = xlb[i]; }
    __syncthreads();

    float acc_rel = 0.f, acc_root = 0.f;
    for (int f = 0; f < FIN; ++f) {
        acc_rel  += aggf[f] * Wrel[f * COUT + lane];
        acc_root += hif[f]  * Wroot[f * COUT + lane];
    }
    float acc = (acc_rel + brel[lane]) + acc_root;
    acc = fmaxf(acc, 0.0f);
    out[(size_t)NB * 3 * N_PTS + ((((size_t)b << 6) | lane) << 12) + i] = acc;
}

extern "C" void kernel_launch(void* const* d_in, const int* in_sizes, int n_in,
                              void* d_out, int out_size, void* d_ws, size_t ws_size,
                              hipStream_t stream) {
    const float* xloc  = nullptr;
    const float* xfeat = nullptr;
    const float* Wrel  = nullptr;
    const float* brel  = nullptr;
    const float* Wroot = nullptr;
    for (int idx = 0; idx < n_in; ++idx) {
        const long long s = in_sizes[idx];
        const float* p = (const float*)d_in[idx];
        if (s == 98304LL || s == 393216LL)          { xloc = p; }
        else if (s == 2097152LL || s == 8388608LL)  { xfeat = p; }
        else if (s == 4288LL || s == 17152LL)       { if (!Wrel) Wrel = p; else Wroot = p; }
        else if (s == 64LL || s == 256LL)           { brel = p; }
    }
    if (!xloc || !xfeat || !Wrel || !brel || !Wroot) {
        xloc  = (const float*)d_in[0];
        xfeat = (const float*)d_in[1];
        Wrel  = (const float*)d_in[2];
        brel  = (const float*)d_in[3];
        Wroot = (const float*)d_in[4];
    }

    const size_t KNN_BYTES = (size_t)NB * N_PTS * KNN * sizeof(u16);  // 1.31 MB
    if (d_ws != nullptr && ws_size >= KNN_BYTES) {
        u16* knn_ws = (u16*)d_ws;
        knn4_kernel<<<dim3(NB * N_PTS / 4), dim3(64), 0, stream>>>(xloc, knn_ws);
        conv_kernel<<<dim3(NB * N_PTS), dim3(64), 0, stream>>>(
            xloc, xfeat, Wrel, brel, Wroot, knn_ws, (float*)d_out);
    } else {
        pcd_all<<<dim3(NB * N_PTS), dim3(64), 0, stream>>>(
            xloc, xfeat, Wrel, brel, Wroot, (float*)d_out);
    }
}